// Round 7
// baseline (153.327 us; speedup 1.0000x reference)
//
#include <hip/hip_runtime.h>
#include <hip/hip_bf16.h>

// BiPairwiseNegativeCELoss on MI355X.
// Inputs: q, d, nd : [16384, 128] fp32. Output: scalar fp32 loss.
// loss = 0.5 * ( mean(softplus(q.nd_row - q.d_row))
//              + mean(softplus(max_c(q_b . d_c, diag -1e6) - q_b.d_b)) )
//
// R15: offload 1/4 of B to the L1/L2 path. R14 (512-thr, 32 rows/wave,
// 4 waves/SIMD, no spill: VGPR 48, FETCH 18.5MB) fixed occupancy but the
// wall stayed 60us / MfmaUtil 48%: per CU per chunk, LDS reads = 256
// ds_read_b128 ~ 3072 cyc now EXCEED MFMA 2483 cyc (LDS traffic doubled when
// rows/wave halved -- every wave reads the whole 16KB B chunk). MfmaUtil is
// structurally capped at 81% in that shape. Fix: read ks=3 (k 96..127) of B
// directly from global per lane (bf16x8). The B chunk is 16KB, L1-resident,
// and co-resident blocks share the same col-group -> cache reuse is high
// (guide Common-mistake #7: don't LDS-stage what caches serve). LDS read
// demand drops to 2304 cyc; direct path ~64KB/CU/chunk via L1/L2 (~0.5-1.1k
// cyc); MFMA 2483 becomes the max pipe. bdir loads issue BEFORE a counted
// WAITVM(4) (queue = 2 old stage + 4 fresh bdir -> waits only the stage),
// ~300-500 cyc to land before first use; ks3 is last in the accumulation
// chain (order ks0->1->2->3 preserved => bitwise identical to R14).
// Staging shrinks to 12KB/chunk (threads with kseg_g>=12 predicated off;
// their LDS slots are never read). Regs ~84 combined -- safe in the 128
// tier (NOT re-adding bnxt; keep the fit certain).
// Decisive counters: VGPR 70-90 + FETCH ~18-24MB (fit) and MfmaUtil 58-70.
// Same numerics (absmax must stay 0.0).

#define BATCH 16384
#define DDIM  128
#define ROWS_PER_BLOCK 256       // 8 waves x 32 rows
#define COLS_PER_BLOCK 1024      // 16 col-groups
#define CHUNK_COLS 64            // 64 cols x 128 K per chunk
#define NCHUNKS (COLS_PER_BLOCK / CHUNK_COLS)   // 16
#define CHUNK_USHORTS (CHUNK_COLS * DDIM)       // 8192
#define NCG (BATCH / COLS_PER_BLOCK)            // 16
#define NRG (BATCH / ROWS_PER_BLOCK)            // 64
#define NPREP 2048                               // prep blocks (8 rows each)
#define NRED  64                                 // reduce blocks

typedef __attribute__((ext_vector_type(8))) short bf16x8;   // 8 bf16 = 4 VGPRs
typedef __attribute__((ext_vector_type(4))) float f32x4;

__device__ __forceinline__ float softplus_f(float x) {
    return (x > 0.0f) ? x + log1pf(expf(-x)) : log1pf(expf(x));
}

__device__ __forceinline__ ushort f2bf_rne(float x) {
    unsigned u = __float_as_uint(x);
    unsigned r = (u + 0x7FFFu + ((u >> 16) & 1u)) >> 16;
    return (ushort)r;
}

#define WAITVM(n) do { \
        __builtin_amdgcn_s_waitcnt((n) | (7 << 4) | (15 << 8)); \
        asm volatile("" ::: "memory"); \
    } while (0)

#define BARRIER() do { \
        __builtin_amdgcn_s_barrier(); \
        asm volatile("" ::: "memory"); \
    } while (0)

// ---------------------------------------------------------------------------
// Kernel A: pairwise dots (fp32 exact), loss1 block partials, bf16 casts.
// 2048 blocks x 256 threads. Block owns 8 rows; 32 threads per row.
// Also zeroes the reduce ticket for this iteration.
// ---------------------------------------------------------------------------
__global__ __launch_bounds__(256) void prep_kernel(
    const float* __restrict__ q, const float* __restrict__ d,
    const float* __restrict__ nd,
    ushort* __restrict__ qb, ushort* __restrict__ db,
    float* __restrict__ pos, float* __restrict__ loss1_part,
    unsigned* __restrict__ ticket)
{
    const int t   = threadIdx.x;
    const int sub = t >> 5;                      // row 0..7 within block
    const int ln  = t & 31;                      // 32 threads per row
    const int row = blockIdx.x * 8 + sub;
    const size_t idx = (size_t)row * DDIM + ln * 4;

    if (blockIdx.x == 0 && t == 0) ticket[0] = 0u;

    float4 a = *(const float4*)(q  + idx);
    float4 b = *(const float4*)(d  + idx);
    float4 c = *(const float4*)(nd + idx);

    ushort4 o;
    o.x = f2bf_rne(a.x); o.y = f2bf_rne(a.y);
    o.z = f2bf_rne(a.z); o.w = f2bf_rne(a.w);
    *(ushort4*)(qb + idx) = o;
    ushort4 p;
    p.x = f2bf_rne(b.x); p.y = f2bf_rne(b.y);
    p.z = f2bf_rne(b.z); p.w = f2bf_rne(b.w);
    *(ushort4*)(db + idx) = p;

    float ps = a.x * b.x + a.y * b.y + a.z * b.z + a.w * b.w;
    float ns = a.x * c.x + a.y * c.y + a.z * c.z + a.w * c.w;
    ps += __shfl_xor(ps, 1); ps += __shfl_xor(ps, 2);
    ps += __shfl_xor(ps, 4); ps += __shfl_xor(ps, 8);
    ps += __shfl_xor(ps, 16);
    ns += __shfl_xor(ns, 1); ns += __shfl_xor(ns, 2);
    ns += __shfl_xor(ns, 4); ns += __shfl_xor(ns, 8);
    ns += __shfl_xor(ns, 16);

    float contrib = 0.0f;
    if (ln == 0) {
        pos[row] = ps;                     // == scores[b][b], exact fp32
        contrib = softplus_f(ns - ps);
    }
    contrib += __shfl_xor(contrib, 32);    // combine the wave's two rows

    __shared__ float red[4];
    if ((t & 63) == 0) red[t >> 6] = contrib;
    __syncthreads();
    if (t == 0)
        loss1_part[blockIdx.x] = red[0] + red[1] + red[2] + red[3];
}

// ---------------------------------------------------------------------------
// Kernel B: fused GEMM + row-max. 1024 blocks x 512 threads. Block
// (rg = bx&63, cg = bx>>6): rows [rg*256,+256), cols [cg*1024,+1024).
// Wave w owns 32 rows (A in registers, whole K). B: ks 0-2 staged in LDS
// (2x16KB double buffer, XOR-swizzled, 12KB live per chunk); ks 3 read
// directly from global (L1/L2-resident) per lane, prefetched at chunk top
// behind a counted WAITVM(4).
// ---------------------------------------------------------------------------
__global__ __launch_bounds__(512, 4) void inbatch_kernel(
    const ushort* __restrict__ qb, const ushort* __restrict__ db,
    float* __restrict__ partials)
{
    __shared__ ushort stg[2][CHUNK_USHORTS];   // 2 x 16 KB (12 KB live each)

    const int t      = threadIdx.x;            // 0..511
    const int w      = t >> 6;                 // wave 0..7
    const int lane16 = t & 15;
    const int quad   = (t >> 4) & 3;
    const int rg     = blockIdx.x & 63;
    const int cg     = blockIdx.x >> 6;
    const int rows0  = rg * ROWS_PER_BLOCK + w * 32;   // this wave's 32 rows
    const int col0   = cg * COLS_PER_BLOCK;

    // A fragments: lane l holds Q[rows0 + rs*16 + (l&15)][ks*32 + quad*8 + j]
    bf16x8 afrag[2][4];
#pragma unroll
    for (int rs = 0; rs < 2; ++rs)
#pragma unroll
        for (int ks = 0; ks < 4; ++ks)
            afrag[rs][ks] = *(const bf16x8*)(
                qb + (size_t)(rows0 + rs * 16 + lane16) * DDIM + ks * 32 + quad * 8);

    // staging: thread t handles 16B segs i*512+t; col = i*32 + (t>>4),
    // logical kseg = (t&15) ^ ((t>>4)&15) (invariant in i). Threads whose
    // kseg >= 12 carry the ks3 quarter -- never read from LDS -> masked off.
    const int  kseg_g     = (t & 15) ^ ((t >> 4) & 15);
    const bool stage_live = (kseg_g < 12);     // every wave has live lanes
    const int  lane_elem  = (t >> 4) * DDIM + kseg_g * 8;
    const ushort* dbase   = db + (size_t)col0 * DDIM;    // uniform base

    // stage chunk cc of B into LDS buffer bb (dest: wave-uniform + lane*16B)
#define STAGE(cc, bb) do { \
        if (stage_live) { \
            const ushort* _s = dbase + (size_t)(cc) * CHUNK_USHORTS; \
            _Pragma("unroll") \
            for (int _i = 0; _i < 2; ++_i) \
                __builtin_amdgcn_global_load_lds( \
                    (const __attribute__((address_space(1))) void*)(_s + _i * 4096 + lane_elem), \
                    (__attribute__((address_space(3))) void*)(&stg[bb][0] + (_i * 512 + w * 64) * 8), \
                    16, 0, 0); \
        } \
    } while (0)

    // ds_read bases for ks 0..2 (ushort offsets)
    int dsbase[3];
#pragma unroll
    for (int ks = 0; ks < 3; ++ks)
        dsbase[ks] = lane16 * DDIM + (((ks * 4 + quad) ^ lane16) * 8);

    // direct-B per-lane pointer: row = col-index + lane16, elems 96 + quad*8
    const ushort* dcol = db + (size_t)col0 * DDIM + lane16 * DDIM + 96 + quad * 8;

    // diagonal handling: tile (ch,ct) is on this wave's diagonal iff
    // ch*4 + ct == dt + rs, where dt = (rows0-col0)/16 (valid iff diagblk).
    const bool diagblk = ((rows0 >> 10) == cg);
    const int  dt      = (rows0 - col0) >> 4;

    const f32x4 zinit = {0.0f, 0.0f, 0.0f, 0.0f};

    float runmax[2][4];
#pragma unroll
    for (int rs = 0; rs < 2; ++rs)
#pragma unroll
        for (int r = 0; r < 4; ++r) runmax[rs][r] = -3.0e38f;

    STAGE(0, 0);                             // prologue

    for (int ch = 0; ch < NCHUNKS; ++ch) {
        // prefetch this chunk's ks3 B-tiles from global (L1/L2). Issued
        // BEFORE the counted wait so the wait doesn't stall on them.
        bf16x8 bdir[4];
#pragma unroll
        for (int ct = 0; ct < 4; ++ct)
            bdir[ct] = *(const bf16x8*)(dcol + (size_t)ch * CHUNK_USHORTS + ct * 2048);

        // vmcnt queue: [stage(ch) x2 oldest, bdir x4] -> wait to 4 drains
        // exactly the stage loads; bdir stays in flight.
        WAITVM(4);
        BARRIER();                           // chunk ch visible; buf ch^1 free
        if (ch + 1 < NCHUNKS)
            STAGE(ch + 1, (ch + 1) & 1);     // lands under this compute phase

        const ushort* buf = &stg[ch & 1][0];

#pragma unroll
        for (int ct = 0; ct < 4; ++ct) {
            bf16x8 bcur[3];
#pragma unroll
            for (int ks = 0; ks < 3; ++ks)
                bcur[ks] = *(const bf16x8*)(buf + dsbase[ks] + ct * 2048);

            __builtin_amdgcn_s_setprio(1);
#pragma unroll
            for (int rs = 0; rs < 2; ++rs) {
                f32x4 s = __builtin_amdgcn_mfma_f32_16x16x32_bf16(
                    afrag[rs][0], bcur[0], zinit, 0, 0, 0);
                s = __builtin_amdgcn_mfma_f32_16x16x32_bf16(
                    afrag[rs][1], bcur[1], s, 0, 0, 0);
                s = __builtin_amdgcn_mfma_f32_16x16x32_bf16(
                    afrag[rs][2], bcur[2], s, 0, 0, 0);
                s = __builtin_amdgcn_mfma_f32_16x16x32_bf16(
                    afrag[rs][3], bdir[ct], s, 0, 0, 0);   // ks3 from global
                if (diagblk && (ch * 4 + ct == dt + rs)) {   // diagonal: -1e6
#pragma unroll
                    for (int r = 0; r < 4; ++r)
                        if (quad * 4 + r == lane16) s[r] -= 1.0e6f;
                }
#pragma unroll
                for (int r = 0; r < 4; ++r)
                    runmax[rs][r] = fmaxf(runmax[rs][r], s[r]);
            }
            __builtin_amdgcn_s_setprio(0);
        }
    }
#undef STAGE

    // reduce max across the 16 lanes (cols) of each quad-group
#pragma unroll
    for (int rs = 0; rs < 2; ++rs)
#pragma unroll
        for (int r = 0; r < 4; ++r) {
            float m = runmax[rs][r];
            m = fmaxf(m, __shfl_xor(m, 1));
            m = fmaxf(m, __shfl_xor(m, 2));
            m = fmaxf(m, __shfl_xor(m, 4));
            m = fmaxf(m, __shfl_xor(m, 8));
            runmax[rs][r] = m;
        }

    // partial row-max for this col-group -> global [NCG][BATCH]
    if (lane16 == 0) {
#pragma unroll
        for (int rs = 0; rs < 2; ++rs)
#pragma unroll
            for (int r = 0; r < 4; ++r)
                partials[(size_t)cg * BATCH + rows0 + rs * 16 + quad * 4 + r] =
                    runmax[rs][r];
    }
}

// ---------------------------------------------------------------------------
// Kernel C: combine col-group partials, softplus, per-block sums; the LAST
// block (device-scope atomic ticket) also folds in loss1_part and writes the
// final scalar. Summation order identical to the old finalize_kernel.
// ---------------------------------------------------------------------------
__global__ __launch_bounds__(256) void reduce_fin_kernel(
    const float* __restrict__ partials, const float* __restrict__ pos,
    const float* __restrict__ loss1_part,
    float* __restrict__ red_part, unsigned* __restrict__ ticket,
    float* __restrict__ out)
{
    const int t = threadIdx.x;
    const int r = blockIdx.x * 256 + t;
    float fm = partials[r];
#pragma unroll
    for (int cgi = 1; cgi < NCG; ++cgi)
        fm = fmaxf(fm, partials[(size_t)cgi * BATCH + r]);
    float c = softplus_f(fm - pos[r]);
    c += __shfl_xor(c, 1);  c += __shfl_xor(c, 2);
    c += __shfl_xor(c, 4);  c += __shfl_xor(c, 8);
    c += __shfl_xor(c, 16); c += __shfl_xor(c, 32);

    __shared__ float red[4];
    __shared__ int lastflag;
    if ((t & 63) == 0) red[t >> 6] = c;
    __syncthreads();
    if (t == 0) {
        float bs = red[0] + red[1] + red[2] + red[3];
        atomicExch(&red_part[blockIdx.x], bs);   // device-scope visible
        __threadfence();
        unsigned old = atomicAdd(ticket, 1u);
        lastflag = (old == NRED - 1) ? 1 : 0;
    }
    __syncthreads();
    if (lastflag) {
        float s = 0.0f;
#pragma unroll
        for (int i = 0; i < NPREP / 256; ++i)
            s += loss1_part[i * 256 + t];
        if (t < NRED) s += atomicAdd(&red_part[t], 0.0f);  // coherent read
        s += __shfl_xor(s, 1);  s += __shfl_xor(s, 2);
        s += __shfl_xor(s, 4);  s += __shfl_xor(s, 8);
        s += __shfl_xor(s, 16); s += __shfl_xor(s, 32);
        if ((t & 63) == 0) red[t >> 6] = s;
        __syncthreads();
        if (t == 0)
            out[0] = (red[0] + red[1] + red[2] + red[3]) * (1.0f / (2.0f * BATCH));
    }
}

extern "C" void kernel_launch(void* const* d_in, const int* in_sizes, int n_in,
                              void* d_out, int out_size, void* d_ws, size_t ws_size,
                              hipStream_t stream)
{
    const float* q  = (const float*)d_in[0];
    const float* d  = (const float*)d_in[1];
    const float* nd = (const float*)d_in[2];
    float* out = (float*)d_out;

    char* ws = (char*)d_ws;
    float*    pos        = (float*)ws;                                 // 64 KB
    ushort*   qb         = (ushort*)(ws + 65536);                      // 4 MB
    ushort*   db         = (ushort*)(ws + 65536 + 4194304);            // 4 MB
    float*    partials   = (float*)(ws + 65536 + 2 * 4194304);         // 1 MB
    float*    loss1_part = (float*)(ws + 65536 + 2 * 4194304 + 1048576);     // 8 KB
    float*    red_part   = (float*)(ws + 65536 + 2 * 4194304 + 1048576 + 8192); // 256 B
    unsigned* ticket     = (unsigned*)(ws + 65536 + 2 * 4194304 + 1048576 + 8192 + 256);

    prep_kernel<<<NPREP, 256, 0, stream>>>(q, d, nd, qb, db, pos, loss1_part, ticket);
    inbatch_kernel<<<NRG * NCG, 512, 0, stream>>>(qb, db, partials);
    reduce_fin_kernel<<<NRED, 256, 0, stream>>>(partials, pos, loss1_part,
                                                red_part, ticket, out);
}

// Round 8
// 131.421 us; speedup vs baseline: 1.1667x; 1.1667x over previous
//
#include <hip/hip_runtime.h>
#include <hip/hip_bf16.h>

// BiPairwiseNegativeCELoss on MI355X.
// Inputs: q, d, nd : [16384, 128] fp32. Output: scalar fp32 loss.
// loss = 0.5 * ( mean(softplus(q.nd_row - q.d_row))
//              + mean(softplus(max_c(q_b . d_c, diag -1e6) - q_b.d_b)) )
//
// R16: R9's counted-vmcnt ring schedule AT R14's occupancy. R15's direct-B
// regressed (86us): per-lane 16-line gather + no latency hiding. Reverted.
// R14 standing state: fit is real (VGPR 48, FETCH 18.5MB, occ 35-40%), wall
// 4550 cyc/phase vs LDS 3072 (67%, largest pipe) + MFMA 2483 (55%) --
// ~1500 cyc/phase is pure serialization (WAITVM(0) drain + 8-wave barrier
// convoy + post-barrier ds_read flood). R9 built the exact cure (4x16KB ring,
// prologue stages 0-2, steady WAITVM(2) = chunk ch+1 ready one-ahead,
// stage(ch+3) post-barrier, ct=3 pre-reads next chunk's tile0 across the
// barrier, bcur/bnxt register pipeline) and was null -- but at 2 waves/SIMD,
// latency-bound, nothing to overlap. At 4 waves/SIMD with pipes 55-67% busy
// it has material to work with. Regs ~90 (afrag 32 + bcur 16 + bnxt 16 +
// runmax 8 + misc) < 128 tier. Safety: pre-read of ch+1 comes after this
// iteration's wait (own loads) + barrier (ALL waves' loads) => block-wide
// visible; buf[(ch+1)&3] not overwritten until iter ch+2's stage(ch+5).
// Decisive: FETCH ~18.5MB (no spill) + MfmaUtil 58-70 + inbatch 42-48us.
// Same shapes/layouts/numerics as R14 (absmax must stay 0.0).

#define BATCH 16384
#define DDIM  128
#define ROWS_PER_BLOCK 256       // 8 waves x 32 rows
#define COLS_PER_BLOCK 1024      // 16 col-groups
#define CHUNK_COLS 64            // 16 KB bf16 per chunk buffer
#define NCHUNKS (COLS_PER_BLOCK / CHUNK_COLS)   // 16
#define CHUNK_USHORTS (CHUNK_COLS * DDIM)       // 8192
#define NCG (BATCH / COLS_PER_BLOCK)            // 16
#define NRG (BATCH / ROWS_PER_BLOCK)            // 64
#define NPREP 2048                               // prep blocks (8 rows each)
#define NRED  64                                 // reduce blocks

typedef __attribute__((ext_vector_type(8))) short bf16x8;   // 8 bf16 = 4 VGPRs
typedef __attribute__((ext_vector_type(4))) float f32x4;

__device__ __forceinline__ float softplus_f(float x) {
    return (x > 0.0f) ? x + log1pf(expf(-x)) : log1pf(expf(x));
}

__device__ __forceinline__ ushort f2bf_rne(float x) {
    unsigned u = __float_as_uint(x);
    unsigned r = (u + 0x7FFFu + ((u >> 16) & 1u)) >> 16;
    return (ushort)r;
}

#define WAITVM(n) do { \
        __builtin_amdgcn_s_waitcnt((n) | (7 << 4) | (15 << 8)); \
        asm volatile("" ::: "memory"); \
    } while (0)

#define BARRIER() do { \
        __builtin_amdgcn_s_barrier(); \
        asm volatile("" ::: "memory"); \
    } while (0)

// ---------------------------------------------------------------------------
// Kernel A: pairwise dots (fp32 exact), loss1 block partials, bf16 casts.
// 2048 blocks x 256 threads. Block owns 8 rows; 32 threads per row.
// Also zeroes the reduce ticket for this iteration.
// ---------------------------------------------------------------------------
__global__ __launch_bounds__(256) void prep_kernel(
    const float* __restrict__ q, const float* __restrict__ d,
    const float* __restrict__ nd,
    ushort* __restrict__ qb, ushort* __restrict__ db,
    float* __restrict__ pos, float* __restrict__ loss1_part,
    unsigned* __restrict__ ticket)
{
    const int t   = threadIdx.x;
    const int sub = t >> 5;                      // row 0..7 within block
    const int ln  = t & 31;                      // 32 threads per row
    const int row = blockIdx.x * 8 + sub;
    const size_t idx = (size_t)row * DDIM + ln * 4;

    if (blockIdx.x == 0 && t == 0) ticket[0] = 0u;

    float4 a = *(const float4*)(q  + idx);
    float4 b = *(const float4*)(d  + idx);
    float4 c = *(const float4*)(nd + idx);

    ushort4 o;
    o.x = f2bf_rne(a.x); o.y = f2bf_rne(a.y);
    o.z = f2bf_rne(a.z); o.w = f2bf_rne(a.w);
    *(ushort4*)(qb + idx) = o;
    ushort4 p;
    p.x = f2bf_rne(b.x); p.y = f2bf_rne(b.y);
    p.z = f2bf_rne(b.z); p.w = f2bf_rne(b.w);
    *(ushort4*)(db + idx) = p;

    float ps = a.x * b.x + a.y * b.y + a.z * b.z + a.w * b.w;
    float ns = a.x * c.x + a.y * c.y + a.z * c.z + a.w * c.w;
    ps += __shfl_xor(ps, 1); ps += __shfl_xor(ps, 2);
    ps += __shfl_xor(ps, 4); ps += __shfl_xor(ps, 8);
    ps += __shfl_xor(ps, 16);
    ns += __shfl_xor(ns, 1); ns += __shfl_xor(ns, 2);
    ns += __shfl_xor(ns, 4); ns += __shfl_xor(ns, 8);
    ns += __shfl_xor(ns, 16);

    float contrib = 0.0f;
    if (ln == 0) {
        pos[row] = ps;                     // == scores[b][b], exact fp32
        contrib = softplus_f(ns - ps);
    }
    contrib += __shfl_xor(contrib, 32);    // combine the wave's two rows

    __shared__ float red[4];
    if ((t & 63) == 0) red[t >> 6] = contrib;
    __syncthreads();
    if (t == 0)
        loss1_part[blockIdx.x] = red[0] + red[1] + red[2] + red[3];
}

// ---------------------------------------------------------------------------
// Kernel B: fused GEMM + row-max. 1024 blocks x 512 threads, 2 blocks/CU
// (16 waves/CU = 4 waves/SIMD). Block (rg = bx&63, cg = bx>>6): rows
// [rg*256,+256), cols [cg*1024,+1024). Wave w owns 32 rows (A in registers,
// whole K). B staged cooperatively: 64-col chunks, 4x16KB LDS ring
// (one-chunk-ahead readiness, counted vmcnt, never 0 until the tail),
// XOR-swizzled 16B k-segments. Intra-chunk bcur/bnxt register pipeline;
// ct=3 pre-reads the NEXT chunk's first tile across the barrier.
// ---------------------------------------------------------------------------
__global__ __launch_bounds__(512, 4) void inbatch_kernel(
    const ushort* __restrict__ qb, const ushort* __restrict__ db,
    float* __restrict__ partials)
{
    __shared__ ushort stg[4][CHUNK_USHORTS];   // 4 x 16 KB = 64 KB

    const int t      = threadIdx.x;            // 0..511
    const int w      = t >> 6;                 // wave 0..7
    const int lane16 = t & 15;
    const int quad   = (t >> 4) & 3;
    const int rg     = blockIdx.x & 63;
    const int cg     = blockIdx.x >> 6;
    const int rows0  = rg * ROWS_PER_BLOCK + w * 32;   // this wave's 32 rows
    const int col0   = cg * COLS_PER_BLOCK;

    // A fragments: lane l holds Q[rows0 + rs*16 + (l&15)][ks*32 + quad*8 + j]
    bf16x8 afrag[2][4];
#pragma unroll
    for (int rs = 0; rs < 2; ++rs)
#pragma unroll
        for (int ks = 0; ks < 4; ++ks)
            afrag[rs][ks] = *(const bf16x8*)(
                qb + (size_t)(rows0 + rs * 16 + lane16) * DDIM + ks * 32 + quad * 8);

    // staging: chunk = 1024 x 16B segments; thread t handles segs i*512 + t
    // (i = 0..1). col = i*32 + (t>>4), LDS slot = t&15, global kseg =
    // (t&15) ^ ((t>>4)&15)  (i*32 is 0 mod 16, so the XOR term is invariant).
    const int lane_elem = (t >> 4) * DDIM + (((t & 15) ^ ((t >> 4) & 15)) * 8);
    const ushort* dbase = db + (size_t)col0 * DDIM;    // uniform base

    // stage chunk cc of B into LDS buffer bb (dest: wave-uniform + lane*16B)
#define STAGE(cc, bb) do { \
        const ushort* _s = dbase + (size_t)(cc) * CHUNK_USHORTS; \
        _Pragma("unroll") \
        for (int _i = 0; _i < 2; ++_i) \
            __builtin_amdgcn_global_load_lds( \
                (const __attribute__((address_space(1))) void*)(_s + _i * 4096 + lane_elem), \
                (__attribute__((address_space(3))) void*)(&stg[bb][0] + (_i * 512 + w * 64) * 8), \
                16, 0, 0); \
    } while (0)

    // ds_read base (ushort offsets); per-(ct,buf) selected by pointer + imm
    int dsbase[4];
#pragma unroll
    for (int ks = 0; ks < 4; ++ks)
        dsbase[ks] = lane16 * DDIM + (((ks * 4 + quad) ^ lane16) * 8);

    // diagonal handling: tile (ch,ct) is on this wave's diagonal iff
    // ch*4 + ct == dt + rs, where dt = (rows0-col0)/16 (valid iff diagblk).
    const bool diagblk = ((rows0 >> 10) == cg);
    const int  dt      = (rows0 - col0) >> 4;

    const f32x4 zinit = {0.0f, 0.0f, 0.0f, 0.0f};

    float runmax[2][4];
#pragma unroll
    for (int rs = 0; rs < 2; ++rs)
#pragma unroll
        for (int r = 0; r < 4; ++r) runmax[rs][r] = -3.0e38f;

    // prologue: stage chunks 0,1,2 into bufs 0,1,2 (issue order = chunk
    // order; vmcnt retires in order, so counted waits identify chunks)
    STAGE(0, 0);
    STAGE(1, 1);
    STAGE(2, 2);

    WAITVM(4);                 // 6 issued; retire 2 -> chunk 0 landed
    BARRIER();                 // chunk 0 block-wide visible

    // registers always hold the CURRENT tile's B fragments
    bf16x8 bcur[4];
#pragma unroll
    for (int ks = 0; ks < 4; ++ks)
        bcur[ks] = *(const bf16x8*)(&stg[0][0] + dsbase[ks]);

    for (int ch = 0; ch < NCHUNKS; ++ch) {
        // steady state: outstanding = stage(ch+1), stage(ch+2) (4 loads).
        // Wait to 2 drains stage(ch+1) -> chunk ch+1 ready ONE AHEAD of use
        // (enables the ct=3 cross-barrier pre-read). Tail: drain all.
        if (ch < NCHUNKS - 2) { WAITVM(2); } else { WAITVM(0); }
        BARRIER();
        // all waves passed barrier => chunk ch-1 fully consumed; safe to
        // overwrite buf[(ch+3)&3] == buf[(ch-1)&3]
        if (ch + 3 < NCHUNKS)
            STAGE(ch + 3, (ch + 3) & 3);

        const ushort* buf  = &stg[ch & 3][0];
        const ushort* bufn = &stg[(ch + 1) & 3][0];

#pragma unroll
        for (int ct = 0; ct < 4; ++ct) {
            // pipeline: read the NEXT tile's fragments under this tile's
            // MFMAs. At ct==3 read the next CHUNK's tile 0 (visible since
            // this iteration's wait+barrier) -- no post-barrier LDS bubble.
            bf16x8 bnxt[4];
            if (ct < 3) {
#pragma unroll
                for (int ks = 0; ks < 4; ++ks)
                    bnxt[ks] = *(const bf16x8*)(buf + dsbase[ks] + (ct + 1) * 2048);
            } else if (ch + 1 < NCHUNKS) {
#pragma unroll
                for (int ks = 0; ks < 4; ++ks)
                    bnxt[ks] = *(const bf16x8*)(bufn + dsbase[ks]);
            }

            __builtin_amdgcn_s_setprio(1);
#pragma unroll
            for (int rs = 0; rs < 2; ++rs) {
                f32x4 s = __builtin_amdgcn_mfma_f32_16x16x32_bf16(
                    afrag[rs][0], bcur[0], zinit, 0, 0, 0);
#pragma unroll
                for (int ks = 1; ks < 4; ++ks)
                    s = __builtin_amdgcn_mfma_f32_16x16x32_bf16(
                        afrag[rs][ks], bcur[ks], s, 0, 0, 0);
                if (diagblk && (ch * 4 + ct == dt + rs)) {   // diagonal: -1e6
#pragma unroll
                    for (int r = 0; r < 4; ++r)
                        if (quad * 4 + r == lane16) s[r] -= 1.0e6f;
                }
#pragma unroll
                for (int r = 0; r < 4; ++r)
                    runmax[rs][r] = fmaxf(runmax[rs][r], s[r]);
            }
            __builtin_amdgcn_s_setprio(0);

            if (ct < 3 || ch + 1 < NCHUNKS) {
#pragma unroll
                for (int ks = 0; ks < 4; ++ks) bcur[ks] = bnxt[ks];
            }
        }
    }
#undef STAGE

    // reduce max across the 16 lanes (cols) of each quad-group
#pragma unroll
    for (int rs = 0; rs < 2; ++rs)
#pragma unroll
        for (int r = 0; r < 4; ++r) {
            float m = runmax[rs][r];
            m = fmaxf(m, __shfl_xor(m, 1));
            m = fmaxf(m, __shfl_xor(m, 2));
            m = fmaxf(m, __shfl_xor(m, 4));
            m = fmaxf(m, __shfl_xor(m, 8));
            runmax[rs][r] = m;
        }

    // partial row-max for this col-group -> global [NCG][BATCH]
    if (lane16 == 0) {
#pragma unroll
        for (int rs = 0; rs < 2; ++rs)
#pragma unroll
            for (int r = 0; r < 4; ++r)
                partials[(size_t)cg * BATCH + rows0 + rs * 16 + quad * 4 + r] =
                    runmax[rs][r];
    }
}

// ---------------------------------------------------------------------------
// Kernel C: combine col-group partials, softplus, per-block sums; the LAST
// block (device-scope atomic ticket) also folds in loss1_part and writes the
// final scalar. Summation order identical to the old finalize_kernel.
// ---------------------------------------------------------------------------
__global__ __launch_bounds__(256) void reduce_fin_kernel(
    const float* __restrict__ partials, const float* __restrict__ pos,
    const float* __restrict__ loss1_part,
    float* __restrict__ red_part, unsigned* __restrict__ ticket,
    float* __restrict__ out)
{
    const int t = threadIdx.x;
    const int r = blockIdx.x * 256 + t;
    float fm = partials[r];
#pragma unroll
    for (int cgi = 1; cgi < NCG; ++cgi)
        fm = fmaxf(fm, partials[(size_t)cgi * BATCH + r]);
    float c = softplus_f(fm - pos[r]);
    c += __shfl_xor(c, 1);  c += __shfl_xor(c, 2);
    c += __shfl_xor(c, 4);  c += __shfl_xor(c, 8);
    c += __shfl_xor(c, 16); c += __shfl_xor(c, 32);

    __shared__ float red[4];
    __shared__ int lastflag;
    if ((t & 63) == 0) red[t >> 6] = c;
    __syncthreads();
    if (t == 0) {
        float bs = red[0] + red[1] + red[2] + red[3];
        atomicExch(&red_part[blockIdx.x], bs);   // device-scope visible
        __threadfence();
        unsigned old = atomicAdd(ticket, 1u);
        lastflag = (old == NRED - 1) ? 1 : 0;
    }
    __syncthreads();
    if (lastflag) {
        float s = 0.0f;
#pragma unroll
        for (int i = 0; i < NPREP / 256; ++i)
            s += loss1_part[i * 256 + t];
        if (t < NRED) s += atomicAdd(&red_part[t], 0.0f);  // coherent read
        s += __shfl_xor(s, 1);  s += __shfl_xor(s, 2);
        s += __shfl_xor(s, 4);  s += __shfl_xor(s, 8);
        s += __shfl_xor(s, 16); s += __shfl_xor(s, 32);
        if ((t & 63) == 0) red[t >> 6] = s;
        __syncthreads();
        if (t == 0)
            out[0] = (red[0] + red[1] + red[2] + red[3]) * (1.0f / (2.0f * BATCH));
    }
}

extern "C" void kernel_launch(void* const* d_in, const int* in_sizes, int n_in,
                              void* d_out, int out_size, void* d_ws, size_t ws_size,
                              hipStream_t stream)
{
    const float* q  = (const float*)d_in[0];
    const float* d  = (const float*)d_in[1];
    const float* nd = (const float*)d_in[2];
    float* out = (float*)d_out;

    char* ws = (char*)d_ws;
    float*    pos        = (float*)ws;                                 // 64 KB
    ushort*   qb         = (ushort*)(ws + 65536);                      // 4 MB
    ushort*   db         = (ushort*)(ws + 65536 + 4194304);            // 4 MB
    float*    partials   = (float*)(ws + 65536 + 2 * 4194304);         // 1 MB
    float*    loss1_part = (float*)(ws + 65536 + 2 * 4194304 + 1048576);     // 8 KB
    float*    red_part   = (float*)(ws + 65536 + 2 * 4194304 + 1048576 + 8192); // 256 B
    unsigned* ticket     = (unsigned*)(ws + 65536 + 2 * 4194304 + 1048576 + 8192 + 256);

    prep_kernel<<<NPREP, 256, 0, stream>>>(q, d, nd, qb, db, pos, loss1_part, ticket);
    inbatch_kernel<<<NRG * NCG, 512, 0, stream>>>(qb, db, partials);
    reduce_fin_kernel<<<NRED, 256, 0, stream>>>(partials, pos, loss1_part,
                                                red_part, ticket, out);
}